// Round 8
// baseline (6891.691 us; speedup 1.0000x reference)
//
#include <hip/hip_runtime.h>
#include <math.h>

#define NH   4096
#define KCAT 8192
#define TPTS 16
#define NBLK 256   // persistent kernel: 1 block per CU (144 KB LDS each)

typedef unsigned short ushort_t;

// ---------------------------------------------------------------------------
// Wave (64-lane) sum reduction (valid result in lane 0)
// ---------------------------------------------------------------------------
__device__ __forceinline__ float wave_reduce64(float s) {
#pragma unroll
    for (int off = 32; off > 0; off >>= 1)
        s += __shfl_down(s, off, 64);
    return s;
}

// ---------------------------------------------------------------------------
// fp32 -> bf16 (RNE) packing, bf16x8 unpack
// ---------------------------------------------------------------------------
__device__ __forceinline__ unsigned f2bf_pack2(float lo, float hi) {
    unsigned ul = __float_as_uint(lo);
    unsigned uh = __float_as_uint(hi);
    ul = (ul + 0x7fffu + ((ul >> 16) & 1u)) >> 16;
    uh = (uh + 0x7fffu + ((uh >> 16) & 1u)) >> 16;
    return ul | (uh << 16);
}

__device__ __forceinline__ ushort_t bf16_1(float x) {
    unsigned u = __float_as_uint(x);
    return (ushort_t)((u + 0x7fffu + ((u >> 16) & 1u)) >> 16);
}

__device__ __forceinline__ void bf16x8_to_f32(uint4 w, float* f) {
    f[0] = __uint_as_float(w.x << 16); f[1] = __uint_as_float(w.x & 0xffff0000u);
    f[2] = __uint_as_float(w.y << 16); f[3] = __uint_as_float(w.y & 0xffff0000u);
    f[4] = __uint_as_float(w.z << 16); f[5] = __uint_as_float(w.z & 0xffff0000u);
    f[6] = __uint_as_float(w.w << 16); f[7] = __uint_as_float(w.w & 0xffff0000u);
}

// unpack 4 bf16x2 (fwd,bwd per element) -> 4 fwd floats + 4 bwd floats
__device__ __forceinline__ void unpack_u(uint4 v, float* f, float* g) {
    f[0] = __uint_as_float(v.x << 16); g[0] = __uint_as_float(v.x & 0xffff0000u);
    f[1] = __uint_as_float(v.y << 16); g[1] = __uint_as_float(v.y & 0xffff0000u);
    f[2] = __uint_as_float(v.z << 16); g[2] = __uint_as_float(v.z & 0xffff0000u);
    f[3] = __uint_as_float(v.w << 16); g[3] = __uint_as_float(v.w & 0xffff0000u);
}

// ===========================================================================
// PERSISTENT COOPERATIVE ODE KERNEL -- LDS-resident W1, prefetched W2 stream
// 256 blocks x 1024 threads (1 block/CU forced by 144 KB LDS).
//
// r7 counters: 29 us/phase with VALU 7% and ~2 us of real work -> the cost
// was (a) 255 leaders spin-polling ONE gen cacheline in the barrier,
// (b) phase-B W2 load latency fully exposed, (c) 16-way LDS conflict on the
// state-vector reads. r8 fixes:
//   (a) fan-out release: 16 per-leaf gen lines, <=16 pollers each, s_sleep(8)
//   (b) W2 row prefetched into named regs at phase-A top, pinned by
//       sched_barrier(0); completes under phase A + barrier
//   (c) state vector split uSa/uSb (even/odd uint4) -> 16B lane stride, free
// ===========================================================================

// ---- 2-level grid barrier, fan-out release.
// bar: [0..15]*32 leaf counters, 16*32 root, (17+i)*32 per-leaf gen lines.
__device__ __forceinline__ void grid_barrier(unsigned* bar) {
    __syncthreads();
    if (threadIdx.x == 0) {
        const int leaf_id = blockIdx.x >> 4;
        unsigned* leaf  = bar + 32 * leaf_id;
        unsigned* root  = bar + 32 * 16;
        unsigned* mygen = bar + 32 * (17 + leaf_id);
        unsigned g = __hip_atomic_load(mygen, __ATOMIC_RELAXED, __HIP_MEMORY_SCOPE_AGENT);
        if (__hip_atomic_fetch_add(leaf, 1u, __ATOMIC_ACQ_REL, __HIP_MEMORY_SCOPE_AGENT) == 15u) {
            __hip_atomic_store(leaf, 0u, __ATOMIC_RELAXED, __HIP_MEMORY_SCOPE_AGENT);
            if (__hip_atomic_fetch_add(root, 1u, __ATOMIC_ACQ_REL, __HIP_MEMORY_SCOPE_AGENT) == 15u) {
                __hip_atomic_store(root, 0u, __ATOMIC_RELAXED, __HIP_MEMORY_SCOPE_AGENT);
                // fan-out release: one store per leaf line (16 lines)
#pragma unroll
                for (int i = 0; i < 16; ++i)
                    __hip_atomic_store(bar + 32 * (17 + i), g + 1u,
                                       __ATOMIC_RELEASE, __HIP_MEMORY_SCOPE_AGENT);
            }
        }
        while (__hip_atomic_load(mygen, __ATOMIC_ACQUIRE, __HIP_MEMORY_SCOPE_AGENT) == g)
            __builtin_amdgcn_s_sleep(8);
    }
    __syncthreads();
}

__global__ __launch_bounds__(64) void zero_bar(unsigned* bar) {
    for (int i = threadIdx.x; i < 2048; i += 64) bar[i] = 0;
}

// ---- X-macro over i = 0..7 (W2 prefetch regs) ---------------------------
#define REP8(X) X(0) X(1) X(2) X(3) X(4) X(5) X(6) X(7)
#define DECL_P(I)  uint4 wp_##I;
#define LOAD_P(I)  wp_##I = w2r[l + 64 * I];
#define DOTB(I)    { float wf[8], f0[8], f1[8];                               \
                     bf16x8_to_f32(wp_##I, wf);                               \
                     uint4 ua = uSa[l + 64 * I];                              \
                     uint4 ub = uSb[l + 64 * I];                              \
                     unpack_u(ua, f0, f1);                                    \
                     unpack_u(ub, f0 + 4, f1 + 4);                            \
                     _Pragma("unroll")                                        \
                     for (int j = 0; j < 8; ++j) {                            \
                         s0 = fmaf(wf[j], f0[j], s0);                         \
                         s1 = fmaf(wf[j], f1[j], s1);                         \
                     } }

__global__ __launch_bounds__(1024, 4)   // 4 waves/EU min -> 128 VGPR budget
void ode_persistent(
    const float* __restrict__ W1, const float* __restrict__ b1,
    const ushort_t* __restrict__ W2b, const float* __restrict__ b2,
    const float* __restrict__ h_f, const float* __restrict__ h_b,
    const float* __restrict__ tf, const float* __restrict__ tb,
    unsigned* __restrict__ Ugu, unsigned* __restrict__ Vgu,
    unsigned* __restrict__ bar, float* __restrict__ Hg)
{
    __shared__ unsigned uW[16 * 2048];  // 128 KB: 16 W1 rows, bf16x2-packed
    __shared__ uint4 uSa[512];          // 8 KB: state vec even uint4 (elems 8i..8i+3)
    __shared__ uint4 uSb[512];          // 8 KB: state vec odd  uint4 (elems 8i+4..8i+7)

    const int t   = threadIdx.x;  // 0..1023
    const int l   = t & 63;
    const int w   = t >> 6;       // 0..15
    const int row = blockIdx.x * 16 + w;

    // ---- load+convert this wave's W1 row into LDS (fp32 -> bf16x2) ----
    {
        const float2* p0 = (const float2*)(W1 + (size_t)row * NH);
        unsigned* wrow = uW + w * 2048;
#pragma unroll
        for (int k = 0; k < 32; ++k) {
            float2 a = p0[l + 64 * k];
            wrow[l + 64 * k] = f2bf_pack2(a.x, a.y);
        }
    }

    // ---- initial u = bf16(h0): elements 4t..4t+3 -> u4 index t ----
    {
        const float4* hf4 = (const float4*)h_f;
        const float4* hb4 = (const float4*)h_b;
        float4 a = hf4[t];
        float4 b = hb4[t];
        uint4 o;
        o.x = f2bf_pack2(a.x, b.x);
        o.y = f2bf_pack2(a.y, b.y);
        o.z = f2bf_pack2(a.z, b.z);
        o.w = f2bf_pack2(a.w, b.w);
        if (t & 1) uSb[t >> 1] = o; else uSa[t >> 1] = o;
    }

    const float bb1 = b1[row];
    const float bb2 = b2[row];
    float H0 = h_f[row], H1 = h_b[row];
    float A0 = 0.f, A1 = 0.f;

    const uint4* __restrict__ w1r = (const uint4*)(uW + w * 2048);         // LDS
    const uint4* __restrict__ w2r = (const uint4*)(W2b + (size_t)row * NH); // global

    __syncthreads();

    for (int s = 0; s < TPTS - 1; ++s) {
        const float dt0 = tf[s + 1] - tf[s];
        const float dt1 = tb[s + 1] - tb[s];
        for (int st = 0; st < 4; ++st) {

            // --- prefetch this wave's W2 row NOW; completes under phase A ---
            REP8(DECL_P)
            REP8(LOAD_P)
            __builtin_amdgcn_sched_barrier(0);   // pin issue point (no sinking)

            // === Phase A: v = tanh(W1 u + b1), W1 row from LDS ===
            {
                float s0 = 0.f, s1 = 0.f;
#pragma unroll
                for (int i = 0; i < 8; ++i) {
                    int idx = l + 64 * i;
                    uint4 wv = w1r[idx];
                    uint4 ua = uSa[idx];
                    uint4 ub = uSb[idx];
                    float wf[8], f0[8], f1[8];
                    bf16x8_to_f32(wv, wf);
                    unpack_u(ua, f0, f1);
                    unpack_u(ub, f0 + 4, f1 + 4);
#pragma unroll
                    for (int j = 0; j < 8; ++j) {
                        s0 = fmaf(wf[j], f0[j], s0);
                        s1 = fmaf(wf[j], f1[j], s1);
                    }
                }
                s0 = wave_reduce64(s0); s1 = wave_reduce64(s1);
                if (l == 0)
                    Vgu[row] = f2bf_pack2(tanhf(s0 + bb1), tanhf(s1 + bb1));
            }
            grid_barrier(bar);
            {   // restage v: t<512 -> even u4 (uSa), t>=512 -> odd (uSb)
                const uint4* g4 = (const uint4*)Vgu;
                int q = t & 511;
                uint4 v = g4[2 * q + (t >> 9)];
                if (t < 512) uSa[q] = v; else uSb[q] = v;
            }
            __syncthreads();

            // === Phase B: k = W2 v + b2 (W2 from prefetched regs); RK4 ===
            {
                float s0 = 0.f, s1 = 0.f;
                REP8(DOTB)
                s0 = wave_reduce64(s0); s1 = wave_reduce64(s1);
                float k0 = s0 + bb2, k1 = s1 + bb2;   // valid in lane 0
                float wgt = (st == 1 || st == 2) ? 2.f : 1.f;
                if (st == 0) { A0 = H0; A1 = H1; }
                A0 += wgt * (dt0 / 6.f) * k0;
                A1 += wgt * (dt1 / 6.f) * k1;
                float u0, u1;
                if (st == 3) {
                    H0 = A0; H1 = A1;
                    u0 = H0; u1 = H1;
                } else {
                    float cn = (st == 2) ? 1.f : 0.5f;
                    u0 = H0 + cn * dt0 * k0;
                    u1 = H1 + cn * dt1 * k1;
                }
                if (l == 0) Ugu[row] = f2bf_pack2(u0, u1);
            }
            grid_barrier(bar);
            {   // restage u
                const uint4* g4 = (const uint4*)Ugu;
                int q = t & 511;
                uint4 v = g4[2 * q + (t >> 9)];
                if (t < 512) uSa[q] = v; else uSb[q] = v;
            }
            __syncthreads();
        }
    }

    // final h -> Hg (fp32) for the GRU/head tail
    if (l == 0) {
        Hg[row]      = H0;
        Hg[NH + row] = H1;
    }
}

// ===========================================================================
// Fallback path kernels (harness-verified multi-kernel version, unchanged)
// ===========================================================================

__global__ __launch_bounds__(256) void cvt_bf16_kernel(const float* __restrict__ src,
                                                       ushort_t* __restrict__ dst, int n8) {
    int i = blockIdx.x * 256 + threadIdx.x;
    if (i < n8) {
        const float4* s4 = (const float4*)src;
        float4 a = s4[2 * i], b = s4[2 * i + 1];
        uint4 o;
        o.x = f2bf_pack2(a.x, a.y);
        o.y = f2bf_pack2(a.z, a.w);
        o.z = f2bf_pack2(b.x, b.y);
        o.w = f2bf_pack2(b.z, b.w);
        ((uint4*)dst)[i] = o;
    }
}

__global__ __launch_bounds__(256) void init_hu(const float* __restrict__ h_f,
                                               const float* __restrict__ h_b,
                                               float* __restrict__ H,
                                               ushort_t* __restrict__ Ubf) {
    int i = blockIdx.x * 256 + threadIdx.x;
    float a = h_f[i], b = h_b[i];
    H[i]       = a;  H[NH + i]   = b;
    Ubf[i]     = bf16_1(a);
    Ubf[NH + i] = bf16_1(b);
}

__global__ __launch_bounds__(512, 4) void ode_mv1(
    const ushort_t* __restrict__ W1b, const float* __restrict__ b1,
    const ushort_t* __restrict__ Ubf, ushort_t* __restrict__ Vbf)
{
    __shared__ uint4 uS[1024];
    const int t = threadIdx.x;
    {
        const uint4* U4 = (const uint4*)Ubf;
        uS[t]       = U4[t];
        uS[t + 512] = U4[t + 512];
    }
    __syncthreads();

    const int l   = t & 63;
    const int row = blockIdx.x * 8 + (t >> 6);
    const uint4* __restrict__ W4 = (const uint4*)(W1b + (size_t)row * NH);

    float s0 = 0.f, s1 = 0.f;
#pragma unroll
    for (int i = 0; i < 8; ++i) {
        int idx = l + 64 * i;
        uint4 wv = W4[idx];
        uint4 u0 = uS[idx];
        uint4 u1 = uS[512 + idx];
        float wf[8], a0[8], a1[8];
        bf16x8_to_f32(wv, wf);
        bf16x8_to_f32(u0, a0);
        bf16x8_to_f32(u1, a1);
#pragma unroll
        for (int k = 0; k < 8; ++k) {
            s0 += wf[k] * a0[k];
            s1 += wf[k] * a1[k];
        }
    }
    s0 = wave_reduce64(s0);
    s1 = wave_reduce64(s1);
    if (l == 0) {
        float bb = b1[row];
        Vbf[row]      = bf16_1(tanhf(s0 + bb));
        Vbf[NH + row] = bf16_1(tanhf(s1 + bb));
    }
}

__global__ __launch_bounds__(512, 4) void ode_mv2(
    const ushort_t* __restrict__ W2b, const float* __restrict__ b2,
    const ushort_t* __restrict__ Vbf,
    const float* __restrict__ tf, const float* __restrict__ tb, int sidx,
    float wgt, float cnext, int stage,
    float* __restrict__ H, float* __restrict__ ACC,
    ushort_t* __restrict__ Ubf)
{
    __shared__ uint4 vS[1024];
    const int t = threadIdx.x;
    {
        const uint4* V4 = (const uint4*)Vbf;
        vS[t]       = V4[t];
        vS[t + 512] = V4[t + 512];
    }
    __syncthreads();

    const int l   = t & 63;
    const int row = blockIdx.x * 8 + (t >> 6);
    const uint4* __restrict__ W4 = (const uint4*)(W2b + (size_t)row * NH);
    const float dt0 = tf[sidx + 1] - tf[sidx];
    const float dt1 = tb[sidx + 1] - tb[sidx];

    float s0 = 0.f, s1 = 0.f;
#pragma unroll
    for (int i = 0; i < 8; ++i) {
        int idx = l + 64 * i;
        uint4 wv = W4[idx];
        uint4 v0 = vS[idx];
        uint4 v1 = vS[512 + idx];
        float wf[8], a0[8], a1[8];
        bf16x8_to_f32(wv, wf);
        bf16x8_to_f32(v0, a0);
        bf16x8_to_f32(v1, a1);
#pragma unroll
        for (int k = 0; k < 8; ++k) {
            s0 += wf[k] * a0[k];
            s1 += wf[k] * a1[k];
        }
    }
    s0 = wave_reduce64(s0);
    s1 = wave_reduce64(s1);
    if (l == 0) {
        float bb = b2[row];
        float k0 = s0 + bb, k1 = s1 + bb;
        float base0 = (stage == 0) ? H[row]      : ACC[row];
        float base1 = (stage == 0) ? H[NH + row] : ACC[NH + row];
        float a0 = base0 + wgt * (dt0 / 6.f) * k0;
        float a1 = base1 + wgt * (dt1 / 6.f) * k1;
        ACC[row]      = a0;
        ACC[NH + row] = a1;
        if (stage == 3) {
            H[row]      = a0;
            H[NH + row] = a1;
            Ubf[row]      = bf16_1(a0);
            Ubf[NH + row] = bf16_1(a1);
        } else {
            Ubf[row]      = bf16_1(H[row]      + cnext * dt0 * k0);
            Ubf[NH + row] = bf16_1(H[NH + row] + cnext * dt1 * k1);
        }
    }
}

__global__ __launch_bounds__(256) void init_h_kernel(const float* __restrict__ h_f,
                                                     const float* __restrict__ h_b,
                                                     float* __restrict__ H) {
    int i = blockIdx.x * 256 + threadIdx.x;
    H[i]      = h_f[i];
    H[NH + i] = h_b[i];
}

__global__ __launch_bounds__(256) void rk4_mv1_f32(
    const float* __restrict__ W1, const float* __restrict__ b1,
    const float* __restrict__ H,  const float* __restrict__ Kv,
    const float* __restrict__ tf, const float* __restrict__ tb,
    int tidx, float coef, int useK,
    float* __restrict__ V)
{
    const int row  = blockIdx.x * 4 + (threadIdx.x >> 6);
    const int lane = threadIdx.x & 63;
    const float a0 = coef * (tf[tidx + 1] - tf[tidx]);
    const float a1 = coef * (tb[tidx + 1] - tb[tidx]);

    const float4* __restrict__ W4 = (const float4*)(W1 + (size_t)row * NH);
    const float4* __restrict__ x0 = (const float4*)(H);
    const float4* __restrict__ x1 = (const float4*)(H + NH);
    const float4* __restrict__ k0 = (const float4*)(Kv);
    const float4* __restrict__ k1 = (const float4*)(Kv + NH);

    float s0 = 0.f, s1 = 0.f;
    if (useK) {
#pragma unroll 8
        for (int i = 0; i < NH / 4 / 64; ++i) {
            int idx = lane + i * 64;
            float4 w  = W4[idx];
            float4 h0 = x0[idx], h1 = x1[idx];
            float4 p0 = k0[idx], p1 = k1[idx];
            s0 += w.x * (h0.x + a0 * p0.x) + w.y * (h0.y + a0 * p0.y)
                + w.z * (h0.z + a0 * p0.z) + w.w * (h0.w + a0 * p0.w);
            s1 += w.x * (h1.x + a1 * p1.x) + w.y * (h1.y + a1 * p1.y)
                + w.z * (h1.z + a1 * p1.z) + w.w * (h1.w + a1 * p1.w);
        }
    } else {
#pragma unroll 8
        for (int i = 0; i < NH / 4 / 64; ++i) {
            int idx = lane + i * 64;
            float4 w  = W4[idx];
            float4 h0 = x0[idx], h1 = x1[idx];
            s0 += w.x * h0.x + w.y * h0.y + w.z * h0.z + w.w * h0.w;
            s1 += w.x * h1.x + w.y * h1.y + w.z * h1.z + w.w * h1.w;
        }
    }
    s0 = wave_reduce64(s0);
    s1 = wave_reduce64(s1);
    if (lane == 0) {
        float bb = b1[row];
        V[row]      = tanhf(s0 + bb);
        V[NH + row] = tanhf(s1 + bb);
    }
}

__global__ __launch_bounds__(256) void rk4_mv2_f32(
    const float* __restrict__ W2, const float* __restrict__ b2,
    const float* __restrict__ V,
    const float* __restrict__ tf, const float* __restrict__ tb,
    int tidx, float wgt,
    const float* __restrict__ Hbase,
    float* __restrict__ Kout, float* __restrict__ ACC)
{
    const int row  = blockIdx.x * 4 + (threadIdx.x >> 6);
    const int lane = threadIdx.x & 63;

    const float4* __restrict__ W4 = (const float4*)(W2 + (size_t)row * NH);
    const float4* __restrict__ v0 = (const float4*)(V);
    const float4* __restrict__ v1 = (const float4*)(V + NH);

    float s0 = 0.f, s1 = 0.f;
#pragma unroll 8
    for (int i = 0; i < NH / 4 / 64; ++i) {
        int idx = lane + i * 64;
        float4 w = W4[idx];
        float4 a = v0[idx], b = v1[idx];
        s0 += w.x * a.x + w.y * a.y + w.z * a.z + w.w * a.w;
        s1 += w.x * b.x + w.y * b.y + w.z * b.z + w.w * b.w;
    }
    s0 = wave_reduce64(s0);
    s1 = wave_reduce64(s1);
    if (lane == 0) {
        float bb  = b2[row];
        float k0v = s0 + bb;
        float k1v = s1 + bb;
        Kout[row]      = k0v;
        Kout[NH + row] = k1v;
        const float dt0 = tf[tidx + 1] - tf[tidx];
        const float dt1 = tb[tidx + 1] - tb[tidx];
        ACC[row]      = Hbase[row]      + wgt * (dt0 / 6.f) * k0v;
        ACC[NH + row] = Hbase[NH + row] + wgt * (dt1 / 6.f) * k1v;
    }
}

// ---------------------------------------------------------------------------
// GRU / head kernels (fp32 weights; used 1-2x each)
// ---------------------------------------------------------------------------
__global__ __launch_bounds__(256) void build_xcat_kernel(
    const float* __restrict__ x_f, const float* __restrict__ x_b,
    const float* __restrict__ H,
    float* __restrict__ xcat1, float* __restrict__ xcat2)
{
    int i = blockIdx.x * 256 + threadIdx.x;
    float xf = x_f[i], xb = x_b[i];
    xcat1[i]               = xf;
    xcat2[i]               = xf;
    xcat1[KCAT + i]        = xb;
    xcat2[KCAT + i]        = xb;
    xcat1[NH + i]          = H[i];
    xcat1[KCAT + NH + i]   = H[NH + i];
}

__global__ __launch_bounds__(256) void gru_mv1(
    const float* __restrict__ Wi, const float* __restrict__ bi,
    const float* __restrict__ xcat1, const float* __restrict__ H,
    float* __restrict__ G, float* __restrict__ xcat2)
{
    const int row  = blockIdx.x * 4 + (threadIdx.x >> 6);
    const int lane = threadIdx.x & 63;

    const float4* __restrict__ W4 = (const float4*)(Wi + (size_t)row * KCAT);
    const float4* __restrict__ c0 = (const float4*)(xcat1);
    const float4* __restrict__ c1 = (const float4*)(xcat1 + KCAT);

    float s0 = 0.f, s1 = 0.f;
#pragma unroll 8
    for (int i = 0; i < KCAT / 4 / 64; ++i) {
        int idx = lane + i * 64;
        float4 w = W4[idx];
        float4 a = c0[idx], b = c1[idx];
        s0 += w.x * a.x + w.y * a.y + w.z * a.z + w.w * a.w;
        s1 += w.x * b.x + w.y * b.y + w.z * b.z + w.w * b.w;
    }
    s0 = wave_reduce64(s0);
    s1 = wave_reduce64(s1);
    if (lane == 0) {
        float bb = bi[row];
        float g0 = 1.f / (1.f + expf(-(s0 + bb)));
        float g1 = 1.f / (1.f + expf(-(s1 + bb)));
        G[row]      = g0;
        G[NH + row] = g1;
        xcat2[NH + row]        = g0 * H[row];
        xcat2[KCAT + NH + row] = g1 * H[NH + row];
    }
}

__global__ __launch_bounds__(256) void gru_mv2(
    const float* __restrict__ Wi, const float* __restrict__ bi,
    const float* __restrict__ xcat2, const float* __restrict__ H,
    const float* __restrict__ G,
    float* __restrict__ out, float* __restrict__ hcat)
{
    const int row  = blockIdx.x * 4 + (threadIdx.x >> 6);
    const int lane = threadIdx.x & 63;

    const float4* __restrict__ W4 = (const float4*)(Wi + (size_t)row * KCAT);
    const float4* __restrict__ c0 = (const float4*)(xcat2);
    const float4* __restrict__ c1 = (const float4*)(xcat2 + KCAT);

    float s0 = 0.f, s1 = 0.f;
#pragma unroll 8
    for (int i = 0; i < KCAT / 4 / 64; ++i) {
        int idx = lane + i * 64;
        float4 w = W4[idx];
        float4 a = c0[idx], b = c1[idx];
        s0 += w.x * a.x + w.y * a.y + w.z * a.z + w.w * a.w;
        s1 += w.x * b.x + w.y * b.y + w.z * b.z + w.w * b.w;
    }
    s0 = wave_reduce64(s0);
    s1 = wave_reduce64(s1);
    if (lane == 0) {
        float bb  = bi[row];
        float hh0 = tanhf(s0 + bb);
        float hh1 = tanhf(s1 + bb);
        float g0  = G[row], g1 = G[NH + row];
        float hf  = g0 * H[row]      + (1.f - g0) * hh0;
        float hb  = g1 * H[NH + row] + (1.f - g1) * hh1;
        out[NH + row]     = hf;
        out[2 * NH + row] = hb;
        hcat[row]      = hf;
        hcat[NH + row] = hb;
    }
}

__global__ __launch_bounds__(256) void h2o_mv(
    const float* __restrict__ W, const float* __restrict__ b,
    const float* __restrict__ hcat, float* __restrict__ out)
{
    const int row  = blockIdx.x * 4 + (threadIdx.x >> 6);
    const int lane = threadIdx.x & 63;

    const float4* __restrict__ W4 = (const float4*)(W + (size_t)row * KCAT);
    const float4* __restrict__ x4 = (const float4*)(hcat);

    float s = 0.f;
#pragma unroll 8
    for (int i = 0; i < KCAT / 4 / 64; ++i) {
        int idx = lane + i * 64;
        float4 w = W4[idx];
        float4 a = x4[idx];
        s += w.x * a.x + w.y * a.y + w.z * a.z + w.w * a.w;
    }
    s = wave_reduce64(s);
    if (lane == 0)
        out[row] = s + b[row];
}

// ---------------------------------------------------------------------------
extern "C" void kernel_launch(void* const* d_in, const int* in_sizes, int n_in,
                              void* d_out, int out_size, void* d_ws, size_t ws_size,
                              hipStream_t stream) {
    const float* x_f   = (const float*)d_in[0];
    const float* x_b   = (const float*)d_in[1];
    const float* h_f   = (const float*)d_in[2];
    const float* h_b   = (const float*)d_in[3];
    const float* t_f   = (const float*)d_in[4];
    const float* t_b   = (const float*)d_in[5];
    const float* i2h_W = (const float*)d_in[6];
    const float* i2h_b = (const float*)d_in[7];
    const float* h2o_W = (const float*)d_in[8];
    const float* h2o_b = (const float*)d_in[9];
    const float* f_W1  = (const float*)d_in[10];
    const float* f_b1  = (const float*)d_in[11];
    const float* f_W2  = (const float*)d_in[12];
    const float* f_b2  = (const float*)d_in[13];
    float* out = (float*)d_out;

    // ---- workspace layout (all offsets 16B-aligned) ----
    float* ws    = (float*)d_ws;
    float* Hg    = ws;                  // 2*NH fp32
    float* ACCg  = Hg    + 2 * NH;      // 2*NH fp32
    float* Vg32  = ACCg  + 2 * NH;      // 2*NH fp32 (fallback V)
    float* Kg32  = Vg32  + 2 * NH;      // 2*NH fp32 (fallback K)
    float* xcat1 = Kg32  + 2 * NH;      // 2*KCAT
    float* xcat2 = xcat1 + 2 * KCAT;    // 2*KCAT
    float* G     = xcat2 + 2 * KCAT;    // 2*NH
    float* hcat  = G     + 2 * NH;      // KCAT
    float* fend  = hcat  + KCAT;
    ushort_t* Ubf = (ushort_t*)fend;            // 2*NH bf16 (16 KB)
    ushort_t* Vbf = Ubf + 2 * NH;               // 2*NH bf16 (16 KB)
    ushort_t* W1b = Vbf + 2 * NH;               // NH*NH bf16 (32 MB, fallback only)
    ushort_t* W2b = W1b + (size_t)NH * NH;      // NH*NH bf16 (32 MB, coop+fallback)
    size_t need = (size_t)((char*)(W2b + (size_t)NH * NH) - (char*)d_ws);
    const bool fast = ws_size >= need;

    // coop-path small buffers alias the (coop-unused) W1b region
    unsigned* Ugu  = (unsigned*)W1b;               // NH uints (16 KB)
    unsigned* Vgu  = Ugu + NH;                     // NH uints (16 KB)
    unsigned* barp = Vgu + NH;                     // 2048 uints (8 KB)

    dim3 blk(256);
    const int n8 = NH * NH / 8;

    bool ode_done = false;
    if (fast) {
        // one-time W2 fp32 -> bf16 (32 MB, LLC-resident thereafter)
        cvt_bf16_kernel<<<n8 / 256, blk, 0, stream>>>(f_W2, W2b, n8);
        zero_bar<<<1, 64, 0, stream>>>(barp);
        void* kargs[] = { (void*)&f_W1, (void*)&f_b1, (void*)&W2b, (void*)&f_b2,
                          (void*)&h_f,  (void*)&h_b,  (void*)&t_f, (void*)&t_b,
                          (void*)&Ugu,  (void*)&Vgu,  (void*)&barp, (void*)&Hg };
        hipError_t e = hipLaunchCooperativeKernel(ode_persistent, dim3(NBLK), dim3(1024),
                                                  kargs, 0, stream);
        ode_done = (e == hipSuccess);
    }

    if (!ode_done) {
        if (fast) {
            cvt_bf16_kernel<<<n8 / 256, blk, 0, stream>>>(f_W1, W1b, n8);
            cvt_bf16_kernel<<<n8 / 256, blk, 0, stream>>>(f_W2, W2b, n8);
            init_hu<<<NH / 256, blk, 0, stream>>>(h_f, h_b, Hg, Ubf);

            for (int s = 0; s < TPTS - 1; ++s) {
                ode_mv1<<<512, 512, 0, stream>>>(W1b, f_b1, Ubf, Vbf);
                ode_mv2<<<512, 512, 0, stream>>>(W2b, f_b2, Vbf, t_f, t_b, s,
                                                 1.f, 0.5f, 0, Hg, ACCg, Ubf);
                ode_mv1<<<512, 512, 0, stream>>>(W1b, f_b1, Ubf, Vbf);
                ode_mv2<<<512, 512, 0, stream>>>(W2b, f_b2, Vbf, t_f, t_b, s,
                                                 2.f, 0.5f, 1, Hg, ACCg, Ubf);
                ode_mv1<<<512, 512, 0, stream>>>(W1b, f_b1, Ubf, Vbf);
                ode_mv2<<<512, 512, 0, stream>>>(W2b, f_b2, Vbf, t_f, t_b, s,
                                                 2.f, 1.0f, 2, Hg, ACCg, Ubf);
                ode_mv1<<<512, 512, 0, stream>>>(W1b, f_b1, Ubf, Vbf);
                ode_mv2<<<512, 512, 0, stream>>>(W2b, f_b2, Vbf, t_f, t_b, s,
                                                 1.f, 0.0f, 3, Hg, ACCg, Ubf);
            }
        } else {
            const int mv_grid = NH / 4;
            init_h_kernel<<<NH / 256, blk, 0, stream>>>(h_f, h_b, Hg);
            float* H   = Hg;
            float* ACC = ACCg;
            for (int s = 0; s < TPTS - 1; ++s) {
                rk4_mv1_f32<<<mv_grid, blk, 0, stream>>>(f_W1, f_b1, H, Kg32, t_f, t_b, s, 0.0f, 0, Vg32);
                rk4_mv2_f32<<<mv_grid, blk, 0, stream>>>(f_W2, f_b2, Vg32, t_f, t_b, s, 1.0f, H,   Kg32, ACC);
                rk4_mv1_f32<<<mv_grid, blk, 0, stream>>>(f_W1, f_b1, H, Kg32, t_f, t_b, s, 0.5f, 1, Vg32);
                rk4_mv2_f32<<<mv_grid, blk, 0, stream>>>(f_W2, f_b2, Vg32, t_f, t_b, s, 2.0f, ACC, Kg32, ACC);
                rk4_mv1_f32<<<mv_grid, blk, 0, stream>>>(f_W1, f_b1, H, Kg32, t_f, t_b, s, 0.5f, 1, Vg32);
                rk4_mv2_f32<<<mv_grid, blk, 0, stream>>>(f_W2, f_b2, Vg32, t_f, t_b, s, 2.0f, ACC, Kg32, ACC);
                rk4_mv1_f32<<<mv_grid, blk, 0, stream>>>(f_W1, f_b1, H, Kg32, t_f, t_b, s, 1.0f, 1, Vg32);
                rk4_mv2_f32<<<mv_grid, blk, 0, stream>>>(f_W2, f_b2, Vg32, t_f, t_b, s, 1.0f, ACC, Kg32, ACC);
                float* tmp = H; H = ACC; ACC = tmp;
            }
            if (H != Hg) {
                hipMemcpyAsync(Hg, H, 2 * NH * sizeof(float), hipMemcpyDeviceToDevice, stream);
            }
        }
    }

    const int mv_grid = NH / 4;
    build_xcat_kernel<<<NH / 256, blk, 0, stream>>>(x_f, x_b, Hg, xcat1, xcat2);
    gru_mv1<<<mv_grid, blk, 0, stream>>>(i2h_W, i2h_b, xcat1, Hg, G, xcat2);
    gru_mv2<<<mv_grid, blk, 0, stream>>>(i2h_W, i2h_b, xcat2, Hg, G, out, hcat);
    h2o_mv <<<mv_grid, blk, 0, stream>>>(h2o_W, h2o_b, hcat, out);
}

// Round 9
// 1986.157 us; speedup vs baseline: 3.4699x; 3.4699x over previous
//
#include <hip/hip_runtime.h>
#include <math.h>

#define NH   4096
#define KCAT 8192
#define TPTS 16
#define NBLK 256   // persistent kernel: 1 block per CU (144 KB LDS each)

typedef unsigned short ushort_t;

// ---------------------------------------------------------------------------
// Wave (64-lane) sum reduction (valid result in lane 0)
// ---------------------------------------------------------------------------
__device__ __forceinline__ float wave_reduce64(float s) {
#pragma unroll
    for (int off = 32; off > 0; off >>= 1)
        s += __shfl_down(s, off, 64);
    return s;
}

// ---------------------------------------------------------------------------
// fp32 -> bf16 (RNE) packing, bf16x8 unpack
// ---------------------------------------------------------------------------
__device__ __forceinline__ unsigned f2bf_pack2(float lo, float hi) {
    unsigned ul = __float_as_uint(lo);
    unsigned uh = __float_as_uint(hi);
    ul = (ul + 0x7fffu + ((ul >> 16) & 1u)) >> 16;
    uh = (uh + 0x7fffu + ((uh >> 16) & 1u)) >> 16;
    return ul | (uh << 16);
}

__device__ __forceinline__ ushort_t bf16_1(float x) {
    unsigned u = __float_as_uint(x);
    return (ushort_t)((u + 0x7fffu + ((u >> 16) & 1u)) >> 16);
}

__device__ __forceinline__ void bf16x8_to_f32(uint4 w, float* f) {
    f[0] = __uint_as_float(w.x << 16); f[1] = __uint_as_float(w.x & 0xffff0000u);
    f[2] = __uint_as_float(w.y << 16); f[3] = __uint_as_float(w.y & 0xffff0000u);
    f[4] = __uint_as_float(w.z << 16); f[5] = __uint_as_float(w.z & 0xffff0000u);
    f[6] = __uint_as_float(w.w << 16); f[7] = __uint_as_float(w.w & 0xffff0000u);
}

// unpack 4 bf16x2 (fwd,bwd per element) -> 4 fwd floats + 4 bwd floats
__device__ __forceinline__ void unpack_u(uint4 v, float* f, float* g) {
    f[0] = __uint_as_float(v.x << 16); g[0] = __uint_as_float(v.x & 0xffff0000u);
    f[1] = __uint_as_float(v.y << 16); g[1] = __uint_as_float(v.y & 0xffff0000u);
    f[2] = __uint_as_float(v.z << 16); g[2] = __uint_as_float(v.z & 0xffff0000u);
    f[3] = __uint_as_float(v.w << 16); g[3] = __uint_as_float(v.w & 0xffff0000u);
}

// ===========================================================================
// PERSISTENT COOPERATIVE ODE KERNEL -- L2-PRESERVING COHERENCE DESIGN
// 256 blocks x 1024 threads (1 block/CU, 144 KB LDS).
//
// r3-r8 pattern: dur ~= FETCH/hbm_bw every round -> weight-refetch-bound.
// Root cause: the barrier's agent-scope ACQUIRE spin invalidated the
// per-XCD L2 every poll, so W2 (4 MB/XCD, exactly L2-sized) could never
// stay resident and re-streamed from LLC/HBM at ~0.8 TB/s each phase.
//
// r9 design rule: weights are IMMUTABLE -> stale L2 is correct for them.
// Only 16 KB of state is mutable. So:
//   - All mutable cross-block traffic (bar flags, Vgu/Ugu publish+restage)
//     uses agent-scope RELAXED atomics -> executed at LLC (bypass L2),
//     fresh by construction, no fences needed.
//   - Barrier arrivals are RELEASE-only (writeback of dirty lines; weights
//     are clean so they stay). NO acquire/invalidate anywhere in the loop.
//   - Per-XCD L2 keeps W2 permanently -> phase B is L2-hit.
// W1: 16 rows/block in LDS (128 KB). W2: bf16 rows streamed (L2-resident).
// State in split LDS uSa/uSb (r8's bank-conflict fix, conflicts ~0).
// ===========================================================================

// ---- 2-level grid barrier, fan-out release, NO L2 invalidation.
// bar: [0..15]*32 leaf counters, 16*32 root, (17+i)*32 per-leaf gen lines.
__device__ __forceinline__ void grid_barrier(unsigned* bar) {
    __syncthreads();
    if (threadIdx.x == 0) {
        const int leaf_id = blockIdx.x >> 4;
        unsigned* leaf  = bar + 32 * leaf_id;
        unsigned* root  = bar + 32 * 16;
        unsigned* mygen = bar + 32 * (17 + leaf_id);
        unsigned g = __hip_atomic_load(mygen, __ATOMIC_RELAXED, __HIP_MEMORY_SCOPE_AGENT);
        // RELEASE add: flushes this XCD's few dirty lines; does NOT invalidate.
        if (__hip_atomic_fetch_add(leaf, 1u, __ATOMIC_RELEASE, __HIP_MEMORY_SCOPE_AGENT) == 15u) {
            __hip_atomic_store(leaf, 0u, __ATOMIC_RELAXED, __HIP_MEMORY_SCOPE_AGENT);
            if (__hip_atomic_fetch_add(root, 1u, __ATOMIC_RELEASE, __HIP_MEMORY_SCOPE_AGENT) == 15u) {
                __hip_atomic_store(root, 0u, __ATOMIC_RELAXED, __HIP_MEMORY_SCOPE_AGENT);
                // fan-out release: one relaxed store per leaf gen line
#pragma unroll
                for (int i = 0; i < 16; ++i)
                    __hip_atomic_store(bar + 32 * (17 + i), g + 1u,
                                       __ATOMIC_RELAXED, __HIP_MEMORY_SCOPE_AGENT);
            }
        }
        // RELAXED spin: atomic load executes at LLC (sc1) -- no L2 invalidate.
        while (__hip_atomic_load(mygen, __ATOMIC_RELAXED, __HIP_MEMORY_SCOPE_AGENT) == g)
            __builtin_amdgcn_s_sleep(1);
    }
    __syncthreads();
}

__global__ __launch_bounds__(64) void zero_bar(unsigned* bar) {
    for (int i = threadIdx.x; i < 2048; i += 64) bar[i] = 0;
}

__global__ __launch_bounds__(1024)
void ode_persistent(
    const float* __restrict__ W1, const float* __restrict__ b1,
    const ushort_t* __restrict__ W2b, const float* __restrict__ b2,
    const float* __restrict__ h_f, const float* __restrict__ h_b,
    const float* __restrict__ tf, const float* __restrict__ tb,
    unsigned* __restrict__ Ugu, unsigned* __restrict__ Vgu,
    unsigned* __restrict__ bar, float* __restrict__ Hg)
{
    __shared__ unsigned uW[16 * 2048];  // 128 KB: 16 W1 rows, bf16x2-packed
    __shared__ uint4 uSa[512];          // 8 KB: state even uint4 (elems 8i..8i+3)
    __shared__ uint4 uSb[512];          // 8 KB: state odd  uint4 (elems 8i+4..8i+7)

    const int t   = threadIdx.x;  // 0..1023
    const int l   = t & 63;
    const int w   = t >> 6;       // 0..15
    const int row = blockIdx.x * 16 + w;

    // ---- load+convert this wave's W1 row into LDS (fp32 -> bf16x2) ----
    {
        const float2* p0 = (const float2*)(W1 + (size_t)row * NH);
        unsigned* wrow = uW + w * 2048;
#pragma unroll
        for (int k = 0; k < 32; ++k) {
            float2 a = p0[l + 64 * k];
            wrow[l + 64 * k] = f2bf_pack2(a.x, a.y);
        }
    }

    // ---- initial u = bf16(h0): elements 4t..4t+3 -> uint4 index t ----
    {
        const float4* hf4 = (const float4*)h_f;
        const float4* hb4 = (const float4*)h_b;
        float4 a = hf4[t];
        float4 b = hb4[t];
        uint4 o;
        o.x = f2bf_pack2(a.x, b.x);
        o.y = f2bf_pack2(a.y, b.y);
        o.z = f2bf_pack2(a.z, b.z);
        o.w = f2bf_pack2(a.w, b.w);
        if (t & 1) uSb[t >> 1] = o; else uSa[t >> 1] = o;
    }

    const float bb1 = b1[row];
    const float bb2 = b2[row];
    float H0 = h_f[row], H1 = h_b[row];
    float A0 = 0.f, A1 = 0.f;

    const uint4* __restrict__ w1r = (const uint4*)(uW + w * 2048);          // LDS
    const uint4* __restrict__ w2r = (const uint4*)(W2b + (size_t)row * NH); // global (L2-resident)

    __syncthreads();

    for (int s = 0; s < TPTS - 1; ++s) {
        const float dt0 = tf[s + 1] - tf[s];
        const float dt1 = tb[s + 1] - tb[s];
        for (int st = 0; st < 4; ++st) {

            // === Phase A: v = tanh(W1 u + b1), W1 row from LDS ===
            {
                float s0 = 0.f, s1 = 0.f;
#pragma unroll
                for (int i = 0; i < 8; ++i) {
                    int idx = l + 64 * i;
                    uint4 wv = w1r[idx];
                    uint4 ua = uSa[idx];
                    uint4 ub = uSb[idx];
                    float wf[8], f0[8], f1[8];
                    bf16x8_to_f32(wv, wf);
                    unpack_u(ua, f0, f1);
                    unpack_u(ub, f0 + 4, f1 + 4);
#pragma unroll
                    for (int j = 0; j < 8; ++j) {
                        s0 = fmaf(wf[j], f0[j], s0);
                        s1 = fmaf(wf[j], f1[j], s1);
                    }
                }
                s0 = wave_reduce64(s0); s1 = wave_reduce64(s1);
                if (l == 0)
                    __hip_atomic_store(Vgu + row,
                                       f2bf_pack2(tanhf(s0 + bb1), tanhf(s1 + bb1)),
                                       __ATOMIC_RELAXED, __HIP_MEMORY_SCOPE_AGENT);
            }
            grid_barrier(bar);
            {   // restage v: coalesced LLC-bypass reads (16 B/lane), split-LDS store
                const unsigned long long* g8 = (const unsigned long long*)Vgu;
                unsigned long long a = __hip_atomic_load(g8 + 2 * t,
                                        __ATOMIC_RELAXED, __HIP_MEMORY_SCOPE_AGENT);
                unsigned long long b = __hip_atomic_load(g8 + 2 * t + 1,
                                        __ATOMIC_RELAXED, __HIP_MEMORY_SCOPE_AGENT);
                uint4 v;
                v.x = (unsigned)a; v.y = (unsigned)(a >> 32);
                v.z = (unsigned)b; v.w = (unsigned)(b >> 32);
                if (t & 1) uSb[t >> 1] = v; else uSa[t >> 1] = v;
            }
            __syncthreads();

            // === Phase B: k = W2 v + b2 (W2 rows L2-hit); RK4; publish u ===
            {
                float s0 = 0.f, s1 = 0.f;
#pragma unroll
                for (int i = 0; i < 8; ++i) {
                    int idx = l + 64 * i;
                    uint4 wv = w2r[idx];
                    uint4 ua = uSa[idx];
                    uint4 ub = uSb[idx];
                    float wf[8], f0[8], f1[8];
                    bf16x8_to_f32(wv, wf);
                    unpack_u(ua, f0, f1);
                    unpack_u(ub, f0 + 4, f1 + 4);
#pragma unroll
                    for (int j = 0; j < 8; ++j) {
                        s0 = fmaf(wf[j], f0[j], s0);
                        s1 = fmaf(wf[j], f1[j], s1);
                    }
                }
                s0 = wave_reduce64(s0); s1 = wave_reduce64(s1);
                float k0 = s0 + bb2, k1 = s1 + bb2;   // valid in lane 0
                float wgt = (st == 1 || st == 2) ? 2.f : 1.f;
                if (st == 0) { A0 = H0; A1 = H1; }
                A0 += wgt * (dt0 / 6.f) * k0;
                A1 += wgt * (dt1 / 6.f) * k1;
                float u0, u1;
                if (st == 3) {
                    H0 = A0; H1 = A1;
                    u0 = H0; u1 = H1;
                } else {
                    float cn = (st == 2) ? 1.f : 0.5f;
                    u0 = H0 + cn * dt0 * k0;
                    u1 = H1 + cn * dt1 * k1;
                }
                if (l == 0)
                    __hip_atomic_store(Ugu + row, f2bf_pack2(u0, u1),
                                       __ATOMIC_RELAXED, __HIP_MEMORY_SCOPE_AGENT);
            }
            grid_barrier(bar);
            {   // restage u
                const unsigned long long* g8 = (const unsigned long long*)Ugu;
                unsigned long long a = __hip_atomic_load(g8 + 2 * t,
                                        __ATOMIC_RELAXED, __HIP_MEMORY_SCOPE_AGENT);
                unsigned long long b = __hip_atomic_load(g8 + 2 * t + 1,
                                        __ATOMIC_RELAXED, __HIP_MEMORY_SCOPE_AGENT);
                uint4 v;
                v.x = (unsigned)a; v.y = (unsigned)(a >> 32);
                v.z = (unsigned)b; v.w = (unsigned)(b >> 32);
                if (t & 1) uSb[t >> 1] = v; else uSa[t >> 1] = v;
            }
            __syncthreads();
        }
    }

    // final h -> Hg (fp32) for the GRU/head tail (dispatch boundary flushes)
    if (l == 0) {
        Hg[row]      = H0;
        Hg[NH + row] = H1;
    }
}

// ===========================================================================
// Fallback path kernels (harness-verified multi-kernel version, unchanged)
// ===========================================================================

__global__ __launch_bounds__(256) void cvt_bf16_kernel(const float* __restrict__ src,
                                                       ushort_t* __restrict__ dst, int n8) {
    int i = blockIdx.x * 256 + threadIdx.x;
    if (i < n8) {
        const float4* s4 = (const float4*)src;
        float4 a = s4[2 * i], b = s4[2 * i + 1];
        uint4 o;
        o.x = f2bf_pack2(a.x, a.y);
        o.y = f2bf_pack2(a.z, a.w);
        o.z = f2bf_pack2(b.x, b.y);
        o.w = f2bf_pack2(b.z, b.w);
        ((uint4*)dst)[i] = o;
    }
}

__global__ __launch_bounds__(256) void init_hu(const float* __restrict__ h_f,
                                               const float* __restrict__ h_b,
                                               float* __restrict__ H,
                                               ushort_t* __restrict__ Ubf) {
    int i = blockIdx.x * 256 + threadIdx.x;
    float a = h_f[i], b = h_b[i];
    H[i]       = a;  H[NH + i]   = b;
    Ubf[i]     = bf16_1(a);
    Ubf[NH + i] = bf16_1(b);
}

__global__ __launch_bounds__(512, 4) void ode_mv1(
    const ushort_t* __restrict__ W1b, const float* __restrict__ b1,
    const ushort_t* __restrict__ Ubf, ushort_t* __restrict__ Vbf)
{
    __shared__ uint4 uS[1024];
    const int t = threadIdx.x;
    {
        const uint4* U4 = (const uint4*)Ubf;
        uS[t]       = U4[t];
        uS[t + 512] = U4[t + 512];
    }
    __syncthreads();

    const int l   = t & 63;
    const int row = blockIdx.x * 8 + (t >> 6);
    const uint4* __restrict__ W4 = (const uint4*)(W1b + (size_t)row * NH);

    float s0 = 0.f, s1 = 0.f;
#pragma unroll
    for (int i = 0; i < 8; ++i) {
        int idx = l + 64 * i;
        uint4 wv = W4[idx];
        uint4 u0 = uS[idx];
        uint4 u1 = uS[512 + idx];
        float wf[8], a0[8], a1[8];
        bf16x8_to_f32(wv, wf);
        bf16x8_to_f32(u0, a0);
        bf16x8_to_f32(u1, a1);
#pragma unroll
        for (int k = 0; k < 8; ++k) {
            s0 += wf[k] * a0[k];
            s1 += wf[k] * a1[k];
        }
    }
    s0 = wave_reduce64(s0);
    s1 = wave_reduce64(s1);
    if (l == 0) {
        float bb = b1[row];
        Vbf[row]      = bf16_1(tanhf(s0 + bb));
        Vbf[NH + row] = bf16_1(tanhf(s1 + bb));
    }
}

__global__ __launch_bounds__(512, 4) void ode_mv2(
    const ushort_t* __restrict__ W2b, const float* __restrict__ b2,
    const ushort_t* __restrict__ Vbf,
    const float* __restrict__ tf, const float* __restrict__ tb, int sidx,
    float wgt, float cnext, int stage,
    float* __restrict__ H, float* __restrict__ ACC,
    ushort_t* __restrict__ Ubf)
{
    __shared__ uint4 vS[1024];
    const int t = threadIdx.x;
    {
        const uint4* V4 = (const uint4*)Vbf;
        vS[t]       = V4[t];
        vS[t + 512] = V4[t + 512];
    }
    __syncthreads();

    const int l   = t & 63;
    const int row = blockIdx.x * 8 + (t >> 6);
    const uint4* __restrict__ W4 = (const uint4*)(W2b + (size_t)row * NH);
    const float dt0 = tf[sidx + 1] - tf[sidx];
    const float dt1 = tb[sidx + 1] - tb[sidx];

    float s0 = 0.f, s1 = 0.f;
#pragma unroll
    for (int i = 0; i < 8; ++i) {
        int idx = l + 64 * i;
        uint4 wv = W4[idx];
        uint4 v0 = vS[idx];
        uint4 v1 = vS[512 + idx];
        float wf[8], a0[8], a1[8];
        bf16x8_to_f32(wv, wf);
        bf16x8_to_f32(v0, a0);
        bf16x8_to_f32(v1, a1);
#pragma unroll
        for (int k = 0; k < 8; ++k) {
            s0 += wf[k] * a0[k];
            s1 += wf[k] * a1[k];
        }
    }
    s0 = wave_reduce64(s0);
    s1 = wave_reduce64(s1);
    if (l == 0) {
        float bb = b2[row];
        float k0 = s0 + bb, k1 = s1 + bb;
        float base0 = (stage == 0) ? H[row]      : ACC[row];
        float base1 = (stage == 0) ? H[NH + row] : ACC[NH + row];
        float a0 = base0 + wgt * (dt0 / 6.f) * k0;
        float a1 = base1 + wgt * (dt1 / 6.f) * k1;
        ACC[row]      = a0;
        ACC[NH + row] = a1;
        if (stage == 3) {
            H[row]      = a0;
            H[NH + row] = a1;
            Ubf[row]      = bf16_1(a0);
            Ubf[NH + row] = bf16_1(a1);
        } else {
            Ubf[row]      = bf16_1(H[row]      + cnext * dt0 * k0);
            Ubf[NH + row] = bf16_1(H[NH + row] + cnext * dt1 * k1);
        }
    }
}

__global__ __launch_bounds__(256) void init_h_kernel(const float* __restrict__ h_f,
                                                     const float* __restrict__ h_b,
                                                     float* __restrict__ H) {
    int i = blockIdx.x * 256 + threadIdx.x;
    H[i]      = h_f[i];
    H[NH + i] = h_b[i];
}

__global__ __launch_bounds__(256) void rk4_mv1_f32(
    const float* __restrict__ W1, const float* __restrict__ b1,
    const float* __restrict__ H,  const float* __restrict__ Kv,
    const float* __restrict__ tf, const float* __restrict__ tb,
    int tidx, float coef, int useK,
    float* __restrict__ V)
{
    const int row  = blockIdx.x * 4 + (threadIdx.x >> 6);
    const int lane = threadIdx.x & 63;
    const float a0 = coef * (tf[tidx + 1] - tf[tidx]);
    const float a1 = coef * (tb[tidx + 1] - tb[tidx]);

    const float4* __restrict__ W4 = (const float4*)(W1 + (size_t)row * NH);
    const float4* __restrict__ x0 = (const float4*)(H);
    const float4* __restrict__ x1 = (const float4*)(H + NH);
    const float4* __restrict__ k0 = (const float4*)(Kv);
    const float4* __restrict__ k1 = (const float4*)(Kv + NH);

    float s0 = 0.f, s1 = 0.f;
    if (useK) {
#pragma unroll 8
        for (int i = 0; i < NH / 4 / 64; ++i) {
            int idx = lane + i * 64;
            float4 w  = W4[idx];
            float4 h0 = x0[idx], h1 = x1[idx];
            float4 p0 = k0[idx], p1 = k1[idx];
            s0 += w.x * (h0.x + a0 * p0.x) + w.y * (h0.y + a0 * p0.y)
                + w.z * (h0.z + a0 * p0.z) + w.w * (h0.w + a0 * p0.w);
            s1 += w.x * (h1.x + a1 * p1.x) + w.y * (h1.y + a1 * p1.y)
                + w.z * (h1.z + a1 * p1.z) + w.w * (h1.w + a1 * p1.w);
        }
    } else {
#pragma unroll 8
        for (int i = 0; i < NH / 4 / 64; ++i) {
            int idx = lane + i * 64;
            float4 w  = W4[idx];
            float4 h0 = x0[idx], h1 = x1[idx];
            s0 += w.x * h0.x + w.y * h0.y + w.z * h0.z + w.w * h0.w;
            s1 += w.x * h1.x + w.y * h1.y + w.z * h1.z + w.w * h1.w;
        }
    }
    s0 = wave_reduce64(s0);
    s1 = wave_reduce64(s1);
    if (lane == 0) {
        float bb = b1[row];
        V[row]      = tanhf(s0 + bb);
        V[NH + row] = tanhf(s1 + bb);
    }
}

__global__ __launch_bounds__(256) void rk4_mv2_f32(
    const float* __restrict__ W2, const float* __restrict__ b2,
    const float* __restrict__ V,
    const float* __restrict__ tf, const float* __restrict__ tb,
    int tidx, float wgt,
    const float* __restrict__ Hbase,
    float* __restrict__ Kout, float* __restrict__ ACC)
{
    const int row  = blockIdx.x * 4 + (threadIdx.x >> 6);
    const int lane = threadIdx.x & 63;

    const float4* __restrict__ W4 = (const float4*)(W2 + (size_t)row * NH);
    const float4* __restrict__ v0 = (const float4*)(V);
    const float4* __restrict__ v1 = (const float4*)(V + NH);

    float s0 = 0.f, s1 = 0.f;
#pragma unroll 8
    for (int i = 0; i < NH / 4 / 64; ++i) {
        int idx = lane + i * 64;
        float4 w = W4[idx];
        float4 a = v0[idx], b = v1[idx];
        s0 += w.x * a.x + w.y * a.y + w.z * a.z + w.w * a.w;
        s1 += w.x * b.x + w.y * b.y + w.z * b.z + w.w * b.w;
    }
    s0 = wave_reduce64(s0);
    s1 = wave_reduce64(s1);
    if (lane == 0) {
        float bb  = b2[row];
        float k0v = s0 + bb;
        float k1v = s1 + bb;
        Kout[row]      = k0v;
        Kout[NH + row] = k1v;
        const float dt0 = tf[tidx + 1] - tf[tidx];
        const float dt1 = tb[tidx + 1] - tb[tidx];
        ACC[row]      = Hbase[row]      + wgt * (dt0 / 6.f) * k0v;
        ACC[NH + row] = Hbase[NH + row] + wgt * (dt1 / 6.f) * k1v;
    }
}

// ---------------------------------------------------------------------------
// GRU / head kernels (fp32 weights; used 1-2x each)
// ---------------------------------------------------------------------------
__global__ __launch_bounds__(256) void build_xcat_kernel(
    const float* __restrict__ x_f, const float* __restrict__ x_b,
    const float* __restrict__ H,
    float* __restrict__ xcat1, float* __restrict__ xcat2)
{
    int i = blockIdx.x * 256 + threadIdx.x;
    float xf = x_f[i], xb = x_b[i];
    xcat1[i]               = xf;
    xcat2[i]               = xf;
    xcat1[KCAT + i]        = xb;
    xcat2[KCAT + i]        = xb;
    xcat1[NH + i]          = H[i];
    xcat1[KCAT + NH + i]   = H[NH + i];
}

__global__ __launch_bounds__(256) void gru_mv1(
    const float* __restrict__ Wi, const float* __restrict__ bi,
    const float* __restrict__ xcat1, const float* __restrict__ H,
    float* __restrict__ G, float* __restrict__ xcat2)
{
    const int row  = blockIdx.x * 4 + (threadIdx.x >> 6);
    const int lane = threadIdx.x & 63;

    const float4* __restrict__ W4 = (const float4*)(Wi + (size_t)row * KCAT);
    const float4* __restrict__ c0 = (const float4*)(xcat1);
    const float4* __restrict__ c1 = (const float4*)(xcat1 + KCAT);

    float s0 = 0.f, s1 = 0.f;
#pragma unroll 8
    for (int i = 0; i < KCAT / 4 / 64; ++i) {
        int idx = lane + i * 64;
        float4 w = W4[idx];
        float4 a = c0[idx], b = c1[idx];
        s0 += w.x * a.x + w.y * a.y + w.z * a.z + w.w * a.w;
        s1 += w.x * b.x + w.y * b.y + w.z * b.z + w.w * b.w;
    }
    s0 = wave_reduce64(s0);
    s1 = wave_reduce64(s1);
    if (lane == 0) {
        float bb = bi[row];
        float g0 = 1.f / (1.f + expf(-(s0 + bb)));
        float g1 = 1.f / (1.f + expf(-(s1 + bb)));
        G[row]      = g0;
        G[NH + row] = g1;
        xcat2[NH + row]        = g0 * H[row];
        xcat2[KCAT + NH + row] = g1 * H[NH + row];
    }
}

__global__ __launch_bounds__(256) void gru_mv2(
    const float* __restrict__ Wi, const float* __restrict__ bi,
    const float* __restrict__ xcat2, const float* __restrict__ H,
    const float* __restrict__ G,
    float* __restrict__ out, float* __restrict__ hcat)
{
    const int row  = blockIdx.x * 4 + (threadIdx.x >> 6);
    const int lane = threadIdx.x & 63;

    const float4* __restrict__ W4 = (const float4*)(Wi + (size_t)row * KCAT);
    const float4* __restrict__ c0 = (const float4*)(xcat2);
    const float4* __restrict__ c1 = (const float4*)(xcat2 + KCAT);

    float s0 = 0.f, s1 = 0.f;
#pragma unroll 8
    for (int i = 0; i < KCAT / 4 / 64; ++i) {
        int idx = lane + i * 64;
        float4 w = W4[idx];
        float4 a = c0[idx], b = c1[idx];
        s0 += w.x * a.x + w.y * a.y + w.z * a.z + w.w * a.w;
        s1 += w.x * b.x + w.y * b.y + w.z * b.z + w.w * b.w;
    }
    s0 = wave_reduce64(s0);
    s1 = wave_reduce64(s1);
    if (lane == 0) {
        float bb  = bi[row];
        float hh0 = tanhf(s0 + bb);
        float hh1 = tanhf(s1 + bb);
        float g0  = G[row], g1 = G[NH + row];
        float hf  = g0 * H[row]      + (1.f - g0) * hh0;
        float hb  = g1 * H[NH + row] + (1.f - g1) * hh1;
        out[NH + row]     = hf;
        out[2 * NH + row] = hb;
        hcat[row]      = hf;
        hcat[NH + row] = hb;
    }
}

__global__ __launch_bounds__(256) void h2o_mv(
    const float* __restrict__ W, const float* __restrict__ b,
    const float* __restrict__ hcat, float* __restrict__ out)
{
    const int row  = blockIdx.x * 4 + (threadIdx.x >> 6);
    const int lane = threadIdx.x & 63;

    const float4* __restrict__ W4 = (const float4*)(W + (size_t)row * KCAT);
    const float4* __restrict__ x4 = (const float4*)(hcat);

    float s = 0.f;
#pragma unroll 8
    for (int i = 0; i < KCAT / 4 / 64; ++i) {
        int idx = lane + i * 64;
        float4 w = W4[idx];
        float4 a = x4[idx];
        s += w.x * a.x + w.y * a.y + w.z * a.z + w.w * a.w;
    }
    s = wave_reduce64(s);
    if (lane == 0)
        out[row] = s + b[row];
}

// ---------------------------------------------------------------------------
extern "C" void kernel_launch(void* const* d_in, const int* in_sizes, int n_in,
                              void* d_out, int out_size, void* d_ws, size_t ws_size,
                              hipStream_t stream) {
    const float* x_f   = (const float*)d_in[0];
    const float* x_b   = (const float*)d_in[1];
    const float* h_f   = (const float*)d_in[2];
    const float* h_b   = (const float*)d_in[3];
    const float* t_f   = (const float*)d_in[4];
    const float* t_b   = (const float*)d_in[5];
    const float* i2h_W = (const float*)d_in[6];
    const float* i2h_b = (const float*)d_in[7];
    const float* h2o_W = (const float*)d_in[8];
    const float* h2o_b = (const float*)d_in[9];
    const float* f_W1  = (const float*)d_in[10];
    const float* f_b1  = (const float*)d_in[11];
    const float* f_W2  = (const float*)d_in[12];
    const float* f_b2  = (const float*)d_in[13];
    float* out = (float*)d_out;

    // ---- workspace layout (all offsets 16B-aligned) ----
    float* ws    = (float*)d_ws;
    float* Hg    = ws;                  // 2*NH fp32
    float* ACCg  = Hg    + 2 * NH;      // 2*NH fp32
    float* Vg32  = ACCg  + 2 * NH;      // 2*NH fp32 (fallback V)
    float* Kg32  = Vg32  + 2 * NH;      // 2*NH fp32 (fallback K)
    float* xcat1 = Kg32  + 2 * NH;      // 2*KCAT
    float* xcat2 = xcat1 + 2 * KCAT;    // 2*KCAT
    float* G     = xcat2 + 2 * KCAT;    // 2*NH
    float* hcat  = G     + 2 * NH;      // KCAT
    float* fend  = hcat  + KCAT;
    ushort_t* Ubf = (ushort_t*)fend;            // 2*NH bf16 (16 KB)
    ushort_t* Vbf = Ubf + 2 * NH;               // 2*NH bf16 (16 KB)
    ushort_t* W1b = Vbf + 2 * NH;               // NH*NH bf16 (32 MB, fallback only)
    ushort_t* W2b = W1b + (size_t)NH * NH;      // NH*NH bf16 (32 MB, coop+fallback)
    size_t need = (size_t)((char*)(W2b + (size_t)NH * NH) - (char*)d_ws);
    const bool fast = ws_size >= need;

    // coop-path small buffers alias the (coop-unused) W1b region
    unsigned* Ugu  = (unsigned*)W1b;               // NH uints (16 KB)
    unsigned* Vgu  = Ugu + NH;                     // NH uints (16 KB)
    unsigned* barp = Vgu + NH;                     // 2048 uints (8 KB)

    dim3 blk(256);
    const int n8 = NH * NH / 8;

    bool ode_done = false;
    if (fast) {
        // one-time W2 fp32 -> bf16 (32 MB, becomes L2/LLC-resident)
        cvt_bf16_kernel<<<n8 / 256, blk, 0, stream>>>(f_W2, W2b, n8);
        zero_bar<<<1, 64, 0, stream>>>(barp);
        void* kargs[] = { (void*)&f_W1, (void*)&f_b1, (void*)&W2b, (void*)&f_b2,
                          (void*)&h_f,  (void*)&h_b,  (void*)&t_f, (void*)&t_b,
                          (void*)&Ugu,  (void*)&Vgu,  (void*)&barp, (void*)&Hg };
        hipError_t e = hipLaunchCooperativeKernel(ode_persistent, dim3(NBLK), dim3(1024),
                                                  kargs, 0, stream);
        ode_done = (e == hipSuccess);
    }

    if (!ode_done) {
        if (fast) {
            cvt_bf16_kernel<<<n8 / 256, blk, 0, stream>>>(f_W1, W1b, n8);
            cvt_bf16_kernel<<<n8 / 256, blk, 0, stream>>>(f_W2, W2b, n8);
            init_hu<<<NH / 256, blk, 0, stream>>>(h_f, h_b, Hg, Ubf);

            for (int s = 0; s < TPTS - 1; ++s) {
                ode_mv1<<<512, 512, 0, stream>>>(W1b, f_b1, Ubf, Vbf);
                ode_mv2<<<512, 512, 0, stream>>>(W2b, f_b2, Vbf, t_f, t_b, s,
                                                 1.f, 0.5f, 0, Hg, ACCg, Ubf);
                ode_mv1<<<512, 512, 0, stream>>>(W1b, f_b1, Ubf, Vbf);
                ode_mv2<<<512, 512, 0, stream>>>(W2b, f_b2, Vbf, t_f, t_b, s,
                                                 2.f, 0.5f, 1, Hg, ACCg, Ubf);
                ode_mv1<<<512, 512, 0, stream>>>(W1b, f_b1, Ubf, Vbf);
                ode_mv2<<<512, 512, 0, stream>>>(W2b, f_b2, Vbf, t_f, t_b, s,
                                                 2.f, 1.0f, 2, Hg, ACCg, Ubf);
                ode_mv1<<<512, 512, 0, stream>>>(W1b, f_b1, Ubf, Vbf);
                ode_mv2<<<512, 512, 0, stream>>>(W2b, f_b2, Vbf, t_f, t_b, s,
                                                 1.f, 0.0f, 3, Hg, ACCg, Ubf);
            }
        } else {
            const int mv_grid = NH / 4;
            init_h_kernel<<<NH / 256, blk, 0, stream>>>(h_f, h_b, Hg);
            float* H   = Hg;
            float* ACC = ACCg;
            for (int s = 0; s < TPTS - 1; ++s) {
                rk4_mv1_f32<<<mv_grid, blk, 0, stream>>>(f_W1, f_b1, H, Kg32, t_f, t_b, s, 0.0f, 0, Vg32);
                rk4_mv2_f32<<<mv_grid, blk, 0, stream>>>(f_W2, f_b2, Vg32, t_f, t_b, s, 1.0f, H,   Kg32, ACC);
                rk4_mv1_f32<<<mv_grid, blk, 0, stream>>>(f_W1, f_b1, H, Kg32, t_f, t_b, s, 0.5f, 1, Vg32);
                rk4_mv2_f32<<<mv_grid, blk, 0, stream>>>(f_W2, f_b2, Vg32, t_f, t_b, s, 2.0f, ACC, Kg32, ACC);
                rk4_mv1_f32<<<mv_grid, blk, 0, stream>>>(f_W1, f_b1, H, Kg32, t_f, t_b, s, 0.5f, 1, Vg32);
                rk4_mv2_f32<<<mv_grid, blk, 0, stream>>>(f_W2, f_b2, Vg32, t_f, t_b, s, 2.0f, ACC, Kg32, ACC);
                rk4_mv1_f32<<<mv_grid, blk, 0, stream>>>(f_W1, f_b1, H, Kg32, t_f, t_b, s, 1.0f, 1, Vg32);
                rk4_mv2_f32<<<mv_grid, blk, 0, stream>>>(f_W2, f_b2, Vg32, t_f, t_b, s, 1.0f, ACC, Kg32, ACC);
                float* tmp = H; H = ACC; ACC = tmp;
            }
            if (H != Hg) {
                hipMemcpyAsync(Hg, H, 2 * NH * sizeof(float), hipMemcpyDeviceToDevice, stream);
            }
        }
    }

    const int mv_grid = NH / 4;
    build_xcat_kernel<<<NH / 256, blk, 0, stream>>>(x_f, x_b, Hg, xcat1, xcat2);
    gru_mv1<<<mv_grid, blk, 0, stream>>>(i2h_W, i2h_b, xcat1, Hg, G, xcat2);
    gru_mv2<<<mv_grid, blk, 0, stream>>>(i2h_W, i2h_b, xcat2, Hg, G, out, hcat);
    h2o_mv <<<mv_grid, blk, 0, stream>>>(h2o_W, h2o_b, hcat, out);
}